// Round 6
// baseline (134.504 us; speedup 1.0000x reference)
//
#include <hip/hip_runtime.h>
#include <stdint.h>

#define N_ROWS 8192
#define DDIM   512

typedef __bf16 bf16_t;
typedef bf16_t bf16x8 __attribute__((ext_vector_type(8)));
typedef float  f32x16 __attribute__((ext_vector_type(16)));

#define MFMA32 __builtin_amdgcn_mfma_f32_32x32x16_bf16

// ---------------- f32 -> bf16 (RNE) convert, vectorized ----------------
__device__ inline uint16_t f2bf(float f) {
    uint32_t u = __float_as_uint(f);
    u += 0x7FFFu + ((u >> 16) & 1u);
    return (uint16_t)(u >> 16);
}

__global__ void convert_bf16(const float* __restrict__ a, const float* __restrict__ b,
                             uint16_t* __restrict__ abf, uint16_t* __restrict__ bbf) {
    const int quads = N_ROWS * DDIM / 4;
    const int stride = gridDim.x * blockDim.x;
    for (int i = blockIdx.x * blockDim.x + threadIdx.x; i < quads; i += stride) {
        float4 va = ((const float4*)a)[i];
        float4 vb = ((const float4*)b)[i];
        ushort4 ra, rb;
        ra.x = f2bf(va.x); ra.y = f2bf(va.y); ra.z = f2bf(va.z); ra.w = f2bf(va.w);
        rb.x = f2bf(vb.x); rb.y = f2bf(vb.y); rb.z = f2bf(vb.z); rb.w = f2bf(vb.w);
        ((ushort4*)abf)[i] = ra;
        ((ushort4*)bbf)[i] = rb;
    }
}

// ---------------- async global->LDS 16B stage ----------------
__device__ inline void stage16(const uint8_t* g, uint8_t* lds_wave_base) {
#if __has_builtin(__builtin_amdgcn_global_load_lds)
    __builtin_amdgcn_global_load_lds(
        (const __attribute__((address_space(1))) uint32_t*)g,
        (__attribute__((address_space(3))) uint32_t*)lds_wave_base, 16, 0, 0);
#else
    *(int4*)(lds_wave_base) = *(const int4*)g;
#endif
}

// ============================================================================
// 256x256 tile, BK=64, 8 waves (2Mx4N), per-wave 128x64 via 32x32x16 MFMA
// (frag grid 4Mi x 2Nj, K-steps kk=0..3). Register-double-buffered fragments:
// phase kk issues kk+1's 6 ds_read_b128, then MFMAs kk — compiler emits
// counted lgkmcnt, so LDS service overlaps MFMA. ONE barrier per K-tile
// (write-after-read separation for staging), vmcnt(0)+barrier gates next-tile
// residency (drains only loads issued a full tile earlier).
// LDS: buf b at sh + b*65536: A 256x128B [0,32768), B 256x128B [32768,65536).
// Row r granule g at r*128 + (g^(r&7))*16 (both-sides XOR swizzle).
// ============================================================================
__global__ void __launch_bounds__(512, 2)
clip_gemm(const uint16_t* __restrict__ A, const uint16_t* __restrict__ B,
          const float* __restrict__ scale_p,
          float* __restrict__ rowsum, float* __restrict__ colsum,
          float* __restrict__ diag) {
    __shared__ __attribute__((aligned(16))) uint8_t sh[131072];

    const int t    = threadIdx.x;
    const int wave = t >> 6;
    const int lane = t & 63;
    const int wm   = wave >> 2;    // 0..1  (M half: 128 rows)
    const int wn   = wave & 3;     // 0..3  (N slice: 64 cols)
    const int l31  = lane & 31;
    const int hl   = lane >> 5;    // k-half
    const int l7   = lane & 7;

    // 2D-chunked XCD swizzle (proven R5): xcd owns 8bm x 16bn, bm-fastest.
    const int orig = blockIdx.x;               // 0..1023
    const int xcd  = orig & 7;
    const int idx  = orig >> 3;                // 0..127
    const int bm   = (xcd & 3) * 8  + (idx & 7);
    const int bn   = (xcd >> 2) * 16 + (idx >> 3);

    const float s     = *scale_p;
    const float shift = s - 64.0f;

    f32x16 acc[4][2];
#pragma unroll
    for (int mi = 0; mi < 4; ++mi)
#pragma unroll
        for (int nj = 0; nj < 2; ++nj)
#pragma unroll
            for (int q = 0; q < 16; ++q) acc[mi][nj][q] = 0.0f;

    // staging source (inverse-swizzled): thread t supplies row c*64+(t>>3),
    // granule (t&7)^((t>>3)&7) of K-tile kt.
    const int g16 = (((t & 7) ^ ((t >> 3) & 7)) << 4);
    const uint8_t* srcA = (const uint8_t*)A + (size_t)(bm * 256 + (t >> 3)) * 1024 + g16;
    const uint8_t* srcB = (const uint8_t*)B + (size_t)(bn * 256 + (t >> 3)) * 1024 + g16;
    uint8_t* dA = sh + wave * 1024;
    uint8_t* dB = sh + 32768 + wave * 1024;

#define STAGE8(kt, bsel) do {                                                   \
        _Pragma("unroll")                                                       \
        for (int c = 0; c < 4; ++c) {                                           \
            stage16(srcA + (size_t)(kt) * 128 + (size_t)c * 65536,              \
                    dA + (bsel) * 65536 + c * 8192);                            \
            stage16(srcB + (size_t)(kt) * 128 + (size_t)c * 65536,              \
                    dB + (bsel) * 65536 + c * 8192);                            \
        }                                                                       \
    } while (0)

    // fragment base byte offsets (row part)
    const int aRow = (wm * 128 + l31) * 128;          // A rows
    const int bRow = 32768 + (wn * 64 + l31) * 128;   // B rows

    // LOADF: 6 ds_read_b128 for k-step KK (A mi=0..3, B nj=0..1)
#define LOADF(A0, A1, A2, A3, B0, B1, BASE, KK) do {                            \
        const uint8_t* _b = (BASE);                                             \
        const int _cx = ((((KK) * 2) + hl) ^ l7) << 4;                          \
        A0 = *(const bf16x8*)(_b + aRow + 0 * 4096 + _cx);                      \
        A1 = *(const bf16x8*)(_b + aRow + 1 * 4096 + _cx);                      \
        A2 = *(const bf16x8*)(_b + aRow + 2 * 4096 + _cx);                      \
        A3 = *(const bf16x8*)(_b + aRow + 3 * 4096 + _cx);                      \
        B0 = *(const bf16x8*)(_b + bRow + 0 * 4096 + _cx);                      \
        B1 = *(const bf16x8*)(_b + bRow + 1 * 4096 + _cx);                      \
    } while (0)

#define MMA8(A0, A1, A2, A3, B0, B1) do {                                       \
        acc[0][0] = MFMA32(A0, B0, acc[0][0], 0, 0, 0);                         \
        acc[0][1] = MFMA32(A0, B1, acc[0][1], 0, 0, 0);                         \
        acc[1][0] = MFMA32(A1, B0, acc[1][0], 0, 0, 0);                         \
        acc[1][1] = MFMA32(A1, B1, acc[1][1], 0, 0, 0);                         \
        acc[2][0] = MFMA32(A2, B0, acc[2][0], 0, 0, 0);                         \
        acc[2][1] = MFMA32(A2, B1, acc[2][1], 0, 0, 0);                         \
        acc[3][0] = MFMA32(A3, B0, acc[3][0], 0, 0, 0);                         \
        acc[3][1] = MFMA32(A3, B1, acc[3][1], 0, 0, 0);                         \
    } while (0)

    // ---------------- prologue ----------------
    STAGE8(0, 0);
    STAGE8(1, 1);
    asm volatile("s_waitcnt vmcnt(8)" ::: "memory");   // own tile-0 loads done
    __builtin_amdgcn_s_barrier();                      // => all waves' done

    bf16x8 aC0, aC1, aC2, aC3, bC0, bC1;
    bf16x8 aN0, aN1, aN2, aN3, bN0, bN1;
    LOADF(aC0, aC1, aC2, aC3, bC0, bC1, sh, 0);

    // ---------------- main loop: 8 K-tiles ----------------
    for (int tt = 0; tt < 8; ++tt) {
        const uint8_t* base  = sh + (tt & 1) * 65536;
        const uint8_t* obase = sh + ((tt + 1) & 1) * 65536;

        LOADF(aN0, aN1, aN2, aN3, bN0, bN1, base, 1);
        MMA8(aC0, aC1, aC2, aC3, bC0, bC1);                     // kk=0
        LOADF(aC0, aC1, aC2, aC3, bC0, bC1, base, 2);
        MMA8(aN0, aN1, aN2, aN3, bN0, bN1);                     // kk=1
        LOADF(aN0, aN1, aN2, aN3, bN0, bN1, base, 3);
        MMA8(aC0, aC1, aC2, aC3, bC0, bC1);                     // kk=2

        // gate: own tile-(tt+1) staging loads done, then all waves' (barrier).
        // barrier also separates buf-c read issues (above) from staging (below).
        asm volatile("s_waitcnt vmcnt(0)" ::: "memory");
        __builtin_amdgcn_s_barrier();

        if (tt < 6) STAGE8(tt + 2, tt & 1);
        if (tt < 7) LOADF(aC0, aC1, aC2, aC3, bC0, bC1, obase, 0);
        MMA8(aN0, aN1, aN2, aN3, bN0, bN1);                     // kk=3
    }
#undef STAGE8
#undef LOADF
#undef MMA8

    // ---------------- epilogue: exp + reductions ----------------
    // C/D 32x32: col = lane&31, row = (q&3) + 8*(q>>2) + 4*(lane>>5)  (m74/m101)
    float cp0 = 0.f, cp1 = 0.f;
#pragma unroll
    for (int mi = 0; mi < 4; ++mi) {
        float rp[16];
#pragma unroll
        for (int q = 0; q < 16; ++q) rp[q] = 0.f;
#pragma unroll
        for (int q = 0; q < 16; ++q) {
            const float l0 = s * acc[mi][0][q];
            const float l1 = s * acc[mi][1][q];
            const float e0 = __expf(l0 - shift);
            const float e1 = __expf(l1 - shift);
            rp[q] = e0 + e1;
            cp0 += e0;
            cp1 += e1;
        }
        // row reduce: 32 lanes (same hl) share a row
#pragma unroll
        for (int q = 0; q < 16; ++q) {
            float v = rp[q];
            v += __shfl_xor(v, 1);
            v += __shfl_xor(v, 2);
            v += __shfl_xor(v, 4);
            v += __shfl_xor(v, 8);
            v += __shfl_xor(v, 16);
            if (l31 == 0) {
                const int rr = wm * 128 + mi * 32 + (q & 3) + 8 * (q >> 2) + 4 * hl;
                atomicAdd(&rowsum[bm * 256 + rr], v);
            }
        }
    }
    // col reduce: lanes l and l+32 share a col
    cp0 += __shfl_xor(cp0, 32);
    cp1 += __shfl_xor(cp1, 32);
    if (hl == 0) {
        atomicAdd(&colsum[bn * 256 + wn * 64 + l31], cp0);
        atomicAdd(&colsum[bn * 256 + wn * 64 + 32 + l31], cp1);
    }
    // diagonal (only diagonal blocks pay)
    if (bm == bn) {
#pragma unroll
        for (int mi = 0; mi < 4; ++mi)
#pragma unroll
            for (int nj = 0; nj < 2; ++nj)
#pragma unroll
                for (int q = 0; q < 16; ++q) {
                    const int rr = wm * 128 + mi * 32 + (q & 3) + 8 * (q >> 2) + 4 * hl;
                    const int cc = wn * 64 + nj * 32 + l31;
                    if (rr == cc)
                        diag[bm * 256 + rr] = s * acc[mi][nj][q];
                }
    }
}

// ---------------- final reduce: loss scalar (parallel) ----------------
__global__ void clip_finalize(const float* __restrict__ rowsum, const float* __restrict__ colsum,
                              const float* __restrict__ diag, const float* __restrict__ scale_p,
                              float* __restrict__ out) {
    __shared__ float red[4];
    const float s = *scale_p;
    const float shift = s - 64.0f;
    const int i = blockIdx.x * 256 + threadIdx.x;   // grid 32 x 256 = 8192
    float acc = logf(rowsum[i]) + logf(colsum[i]) + 2.f * shift - 2.f * diag[i];
#pragma unroll
    for (int m = 1; m < 64; m <<= 1) acc += __shfl_xor(acc, m);
    const int wave = threadIdx.x >> 6;
    const int lane = threadIdx.x & 63;
    if (lane == 0) red[wave] = acc;
    __syncthreads();
    if (threadIdx.x == 0) {
        atomicAdd(out, (red[0] + red[1] + red[2] + red[3]) / (2.0f * N_ROWS));
    }
}

extern "C" void kernel_launch(void* const* d_in, const int* in_sizes, int n_in,
                              void* d_out, int out_size, void* d_ws, size_t ws_size,
                              hipStream_t stream) {
    const float* img     = (const float*)d_in[0];
    const float* txt     = (const float*)d_in[1];
    const float* scale_p = (const float*)d_in[2];

    uint8_t* ws = (uint8_t*)d_ws;
    uint16_t* Abf   = (uint16_t*)ws;                                  // 8 MB
    uint16_t* Bbf   = (uint16_t*)(ws + (size_t)8 * 1024 * 1024);      // 8 MB
    float*    rowsum = (float*)(ws + (size_t)16 * 1024 * 1024);       // 32 KB
    float*    colsum = rowsum + N_ROWS;                               // 32 KB
    float*    diag   = colsum + N_ROWS;                               // 32 KB
    float*    out    = (float*)d_out;

    hipMemsetAsync(rowsum, 0, 2 * N_ROWS * sizeof(float), stream);
    hipMemsetAsync(out, 0, sizeof(float), stream);
    convert_bf16<<<1024, 256, 0, stream>>>(img, txt, Abf, Bbf);
    clip_gemm<<<1024, 512, 0, stream>>>(Abf, Bbf, scale_p, rowsum, colsum, diag);
    clip_finalize<<<32, 256, 0, stream>>>(rowsum, colsum, diag, scale_p, out);
}

// Round 7
// 104.951 us; speedup vs baseline: 1.2816x; 1.2816x over previous
//
#include <hip/hip_runtime.h>
#include <stdint.h>

#define N_ROWS 8192
#define DDIM   512

typedef __bf16 bf16_t;
typedef bf16_t bf16x8 __attribute__((ext_vector_type(8)));
typedef float  f32x4  __attribute__((ext_vector_type(4)));

#define MFMA16 __builtin_amdgcn_mfma_f32_16x16x32_bf16

// ---------------- f32 -> bf16 (RNE) convert, vectorized ----------------
__device__ inline uint16_t f2bf(float f) {
    uint32_t u = __float_as_uint(f);
    u += 0x7FFFu + ((u >> 16) & 1u);
    return (uint16_t)(u >> 16);
}

__global__ void convert_bf16(const float* __restrict__ a, const float* __restrict__ b,
                             uint16_t* __restrict__ abf, uint16_t* __restrict__ bbf) {
    const int quads = N_ROWS * DDIM / 4;
    const int stride = gridDim.x * blockDim.x;
    for (int i = blockIdx.x * blockDim.x + threadIdx.x; i < quads; i += stride) {
        float4 va = ((const float4*)a)[i];
        float4 vb = ((const float4*)b)[i];
        ushort4 ra, rb;
        ra.x = f2bf(va.x); ra.y = f2bf(va.y); ra.z = f2bf(va.z); ra.w = f2bf(va.w);
        rb.x = f2bf(vb.x); rb.y = f2bf(vb.y); rb.z = f2bf(vb.z); rb.w = f2bf(vb.w);
        ((ushort4*)abf)[i] = ra;
        ((ushort4*)bbf)[i] = rb;
    }
}

// ---------------- async global->LDS 16B stage ----------------
__device__ inline void stage16(const uint8_t* g, uint8_t* lds_wave_base) {
#if __has_builtin(__builtin_amdgcn_global_load_lds)
    __builtin_amdgcn_global_load_lds(
        (const __attribute__((address_space(1))) uint32_t*)g,
        (__attribute__((address_space(3))) uint32_t*)lds_wave_base, 16, 0, 0);
#else
    *(int4*)(lds_wave_base) = *(const int4*)g;
#endif
}

// ============================================================================
// 256x256 tile, BK=64, 8 waves (2Mx4N), 16x16x32 MFMA (frag grid 8i x 4j,
// 2 K-steps/tile). R5's conflict-free read pattern (slot = (kk*4+lg)^(lane&7),
// varies with lane>>4 -> 0 bank conflicts, measured) + R6's pipelined loop:
// register-dbuf'd k-step fragments, 12 ds_read issued ahead of each 32-MFMA
// cluster (compiler emits counted lgkmcnt), ONE vmcnt(0)+barrier per K-tile.
// LDS: buf b at sh+b*65536: A 256x128B [0,32768), B [32768,65536).
// Row r granule g at r*128 + (g^(r&7))*16; staging source inverse-swizzled,
// LDS dest linear (rule #21). 2D-chunked XCD swizzle (proven: FETCH 24.7MB).
// ============================================================================
__global__ void __launch_bounds__(512, 2)
clip_gemm(const uint16_t* __restrict__ A, const uint16_t* __restrict__ B,
          const float* __restrict__ scale_p,
          float* __restrict__ rowsum, float* __restrict__ colsum,
          float* __restrict__ diag) {
    __shared__ __attribute__((aligned(16))) uint8_t sh[131072];

    const int t    = threadIdx.x;
    const int wave = t >> 6;
    const int lane = t & 63;
    const int wm   = wave >> 2;    // 0..1  (M half: 128 rows)
    const int wn   = wave & 3;     // 0..3  (N slice: 64 cols)
    const int lr   = lane & 15;
    const int lg   = lane >> 4;
    const int l7   = lane & 7;

    // 2D-chunked XCD swizzle: xcd owns 8bm x 16bn, bm-fastest.
    const int orig = blockIdx.x;               // 0..1023
    const int xcd  = orig & 7;
    const int idx  = orig >> 3;                // 0..127
    const int bm   = (xcd & 3) * 8  + (idx & 7);
    const int bn   = (xcd >> 2) * 16 + (idx >> 3);

    const float s     = *scale_p;
    const float shift = s - 64.0f;

    f32x4 acc[8][4];
#pragma unroll
    for (int i = 0; i < 8; ++i)
#pragma unroll
        for (int j = 0; j < 4; ++j)
#pragma unroll
            for (int r = 0; r < 4; ++r) acc[i][j][r] = 0.0f;

    // staging source (inverse-swizzled): thread t supplies row c*64+(t>>3),
    // granule (t&7)^((t>>3)&7) of K-tile kt.
    const int g16 = (((t & 7) ^ ((t >> 3) & 7)) << 4);
    const uint8_t* srcA = (const uint8_t*)A + (size_t)(bm * 256 + (t >> 3)) * 1024 + g16;
    const uint8_t* srcB = (const uint8_t*)B + (size_t)(bn * 256 + (t >> 3)) * 1024 + g16;
    uint8_t* dA = sh + wave * 1024;
    uint8_t* dB = sh + 32768 + wave * 1024;

#define STAGE8(kt, bsel) do {                                                   \
        _Pragma("unroll")                                                       \
        for (int c = 0; c < 4; ++c) {                                           \
            stage16(srcA + (size_t)(kt) * 128 + (size_t)c * 65536,              \
                    dA + (bsel) * 65536 + c * 8192);                            \
            stage16(srcB + (size_t)(kt) * 128 + (size_t)c * 65536,              \
                    dB + (bsel) * 65536 + c * 8192);                            \
        }                                                                       \
    } while (0)

    // fragment read offsets: chunk octet (kk*4+lg) ^ (lane&7)  [R5-verified]
    const int x0   = ((lg) ^ l7) << 4;        // kk=0
    const int x1   = ((4 | lg) ^ l7) << 4;    // kk=1
    const int aRow = (wm * 128 + lr) * 128;
    const int bRow = 32768 + (wn * 64 + lr) * 128;

    bf16x8 aC[8], bC[4], aN[8], bN[4];

    // LOAD12: 12 ds_read_b128 for one k-step (A i=0..7, B j=0..3)
#define LOAD12(AF, BF, BASE, X) do {                                            \
        const uint8_t* _b = (BASE);                                             \
        _Pragma("unroll")                                                       \
        for (int i = 0; i < 8; ++i)                                             \
            AF[i] = *(const bf16x8*)(_b + aRow + i * 2048 + (X));               \
        _Pragma("unroll")                                                       \
        for (int j = 0; j < 4; ++j)                                             \
            BF[j] = *(const bf16x8*)(_b + bRow + j * 2048 + (X));               \
    } while (0)

#define MMA32(AF, BF) do {                                                      \
        _Pragma("unroll")                                                       \
        for (int i = 0; i < 8; ++i)                                             \
            _Pragma("unroll")                                                   \
            for (int j = 0; j < 4; ++j)                                         \
                acc[i][j] = MFMA16(AF[i], BF[j], acc[i][j], 0, 0, 0);           \
    } while (0)

    // ---------------- prologue ----------------
    STAGE8(0, 0);
    STAGE8(1, 1);
    asm volatile("s_waitcnt vmcnt(8)" ::: "memory");   // own tile-0 loads done
    __builtin_amdgcn_s_barrier();                      // => all waves'

    LOAD12(aC, bC, sh, x0);                            // tile 0, kk=0

    // ---------------- main loop: 8 K-tiles ----------------
    for (int tt = 0; tt < 8; ++tt) {
        const uint8_t* base  = sh + (tt & 1) * 65536;
        const uint8_t* obase = sh + ((tt + 1) & 1) * 65536;

        LOAD12(aN, bN, base, x1);                      // this tile, kk=1
        __builtin_amdgcn_s_setprio(1);
        MMA32(aC, bC);                                 // kk=0
        __builtin_amdgcn_s_setprio(0);

        // gate: tile tt+1 staging (issued a full tile ago) drained; barrier
        // also separates all read-issues of `base` from its overwrite below.
        asm volatile("s_waitcnt vmcnt(0)" ::: "memory");
        __builtin_amdgcn_s_barrier();

        if (tt < 6) STAGE8(tt + 2, tt & 1);
        if (tt < 7) LOAD12(aC, bC, obase, x0);         // next tile, kk=0
        __builtin_amdgcn_s_setprio(1);
        MMA32(aN, bN);                                 // kk=1
        __builtin_amdgcn_s_setprio(0);
    }
#undef STAGE8
#undef LOAD12
#undef MMA32

    // ---------------- epilogue: exp + reductions ----------------
    // D layout (16x16): col = lr, row = lg*4 + r.
    float cp[4] = {0.f, 0.f, 0.f, 0.f};
#pragma unroll
    for (int i = 0; i < 8; ++i) {
        float rp[4] = {0.f, 0.f, 0.f, 0.f};
#pragma unroll
        for (int j = 0; j < 4; ++j) {
#pragma unroll
            for (int r = 0; r < 4; ++r) {
                const float logit = s * acc[i][j][r];
                const float e = __expf(logit - shift);
                rp[r] += e;
                cp[j] += e;
                if (bm == bn) {
                    const int rr = wm * 128 + i * 16 + lg * 4 + r;
                    const int cc = wn * 64 + j * 16 + lr;
                    if (rr == cc) diag[bm * 256 + rr] = logit;
                }
            }
        }
#pragma unroll
        for (int r = 0; r < 4; ++r) {
            float v = rp[r];
            v += __shfl_xor(v, 1);
            v += __shfl_xor(v, 2);
            v += __shfl_xor(v, 4);
            v += __shfl_xor(v, 8);
            if (lr == 0)
                atomicAdd(&rowsum[bm * 256 + wm * 128 + i * 16 + lg * 4 + r], v);
        }
    }
#pragma unroll
    for (int j = 0; j < 4; ++j) {
        float v = cp[j];
        v += __shfl_xor(v, 16);
        v += __shfl_xor(v, 32);
        if (lg == 0)
            atomicAdd(&colsum[bn * 256 + wn * 64 + j * 16 + lr], v);
    }
}

// ---------------- final reduce: loss scalar (parallel) ----------------
__global__ void clip_finalize(const float* __restrict__ rowsum, const float* __restrict__ colsum,
                              const float* __restrict__ diag, const float* __restrict__ scale_p,
                              float* __restrict__ out) {
    __shared__ float red[4];
    const float s = *scale_p;
    const float shift = s - 64.0f;
    const int i = blockIdx.x * 256 + threadIdx.x;   // grid 32 x 256 = 8192
    float acc = logf(rowsum[i]) + logf(colsum[i]) + 2.f * shift - 2.f * diag[i];
#pragma unroll
    for (int m = 1; m < 64; m <<= 1) acc += __shfl_xor(acc, m);
    const int wave = threadIdx.x >> 6;
    const int lane = threadIdx.x & 63;
    if (lane == 0) red[wave] = acc;
    __syncthreads();
    if (threadIdx.x == 0) {
        atomicAdd(out, (red[0] + red[1] + red[2] + red[3]) / (2.0f * N_ROWS));
    }
}

extern "C" void kernel_launch(void* const* d_in, const int* in_sizes, int n_in,
                              void* d_out, int out_size, void* d_ws, size_t ws_size,
                              hipStream_t stream) {
    const float* img     = (const float*)d_in[0];
    const float* txt     = (const float*)d_in[1];
    const float* scale_p = (const float*)d_in[2];

    uint8_t* ws = (uint8_t*)d_ws;
    uint16_t* Abf   = (uint16_t*)ws;                                  // 8 MB
    uint16_t* Bbf   = (uint16_t*)(ws + (size_t)8 * 1024 * 1024);      // 8 MB
    float*    rowsum = (float*)(ws + (size_t)16 * 1024 * 1024);       // 32 KB
    float*    colsum = rowsum + N_ROWS;                               // 32 KB
    float*    diag   = colsum + N_ROWS;                               // 32 KB
    float*    out    = (float*)d_out;

    hipMemsetAsync(rowsum, 0, 2 * N_ROWS * sizeof(float), stream);
    hipMemsetAsync(out, 0, sizeof(float), stream);
    convert_bf16<<<1024, 256, 0, stream>>>(img, txt, Abf, Bbf);
    clip_gemm<<<1024, 512, 0, stream>>>(Abf, Bbf, scale_p, rowsum, colsum, diag);
    clip_finalize<<<32, 256, 0, stream>>>(rowsum, colsum, diag, scale_p, out);
}